// Round 12
// baseline (248.795 us; speedup 1.0000x reference)
//
#include <hip/hip_runtime.h>
#include <stdint.h>

typedef unsigned short u16;
typedef __attribute__((ext_vector_type(8))) short bf16x8;   // 8 bf16 = 4 VGPR (MFMA A/B frag)
typedef __attribute__((ext_vector_type(4))) float f32x4;    // MFMA C/D frag
typedef __attribute__((ext_vector_type(4))) unsigned short u16x4;

#define DEVI static __device__ __forceinline__

DEVI u16 f2bf(float f){ union{float f; unsigned u;} x; x.f=f;
  unsigned r = x.u + 0x7FFFu + ((x.u>>16)&1u); return (u16)(r>>16); }
// round-half-up bf16 (2 VALU ops): max bias 0.5 ulp, fine at this tolerance
DEVI u16 f2bf_fast(float f){ union{float f; unsigned u;} x; x.f=f;
  return (u16)((x.u + 0x8000u)>>16); }

// ---------------- prep: hidden f32->bf16 + both weight transposes, one dispatch ----
__global__ void __launch_bounds__(256) prep_k(const float* __restrict__ hidden,
      const float* __restrict__ wqkv, const float* __restrict__ wproj,
      u16* __restrict__ Acv, u16* __restrict__ WqkvT, u16* __restrict__ WprojT){
  __shared__ u16 t[32][33];
  int bid = blockIdx.x, tid = threadIdx.x;
  if (bid < 3072){                       // cvt hidden: 8 floats/thread
    int i = bid*2048 + tid*8;
    float4 a = *(const float4*)(hidden+i), b = *(const float4*)(hidden+i+4);
    u16x4 lo = { f2bf(a.x), f2bf(a.y), f2bf(a.z), f2bf(a.w) };
    u16x4 hi = { f2bf(b.x), f2bf(b.y), f2bf(b.z), f2bf(b.w) };
    *(u16x4*)(Acv+i) = lo; *(u16x4*)(Acv+i+4) = hi;
    return;
  }
  const float* in; u16* outp; int C, bx, by;
  if (bid < 4800){ int tt = bid-3072; bx = tt%72; by = tt/72; in = wqkv;  outp = WqkvT;  C = 2304; }
  else           { int tt = bid-4800; bx = tt%24; by = tt/24; in = wproj; outp = WprojT; C = 768;  }
  int tx = tid&31, ty = tid>>5;          // 32 x 8
  int c0 = bx*32, r0 = by*32;
  for (int i=0;i<4;i++)
    t[ty+i*8][tx] = f2bf(in[(size_t)(r0+ty+i*8)*C + c0+tx]);
  __syncthreads();
  for (int i=0;i<4;i++) outp[(size_t)(c0+ty+i*8)*768 + r0+tx] = t[tx][ty+i*8];
}

// ------- merged QKV GEMM (round-12): A direct-from-global, B LDS + VGPR relay ------
// Within a 128x128 tile each A-row feeds exactly ONE wave -> A's LDS round-trip has
// zero sharing; waves load their own A frags straight from global (L2-resident via
// the XCD swizzle; quads cover 64B/row so each instr touches 16 full cache lines).
// B (2-way shared) keeps the relay: next B tile global->VGPR during compute, then
// ds_write after the read barrier -> barriers wait on LDS only. LDS halved to 16KB.
//  n0 < 1536 (Q/K): SWAPPED MFMA operands (reg r along n=d) -> u16x4 into [bh][s][d]
//  n0 >= 1536 (V): normal order (reg r along m=s) -> u16x4 into Vt[bh][d][s]
__global__ void __launch_bounds__(256) qkv_gemm(const u16* __restrict__ A,
      const u16* __restrict__ BT, const float* __restrict__ bias,
      u16* __restrict__ Qw, u16* __restrict__ Kw, u16* __restrict__ Vtw){
  __shared__ u16 Bs[8192];   // [128 n][64 k] 128B rows, granule g holds global g^(row&7)
  const int Kdim = 768;
  int tid = threadIdx.x, lane = tid&63, wave = tid>>6;
  int l15 = lane&15, quad = lane>>4;
  int bid = blockIdx.x;                  // 1152 = 8 xcd x 8 mg x 18 n
  int xcd = bid & 7, slot = bid >> 3;
  int mg = slot & 7, nIdx = slot >> 3;
  int m0 = (xcd*8 + mg)*128, n0 = nIdx*128;
  int wm = (wave>>1)*64, wn = (wave&1)*64;
  bool sw = (n0 < 1536);
  f32x4 acc[4][4] = {};
  const char* Ab = (const char*)A; const char* Bb = (const char*)BT;
  char* BsB = (char*)Bs;
  int rr = tid>>3, gs = tid&7;
  int gsw = (gs ^ (rr&7)) << 4;
  const char* Bg[4];
  for (int h=0;h<4;h++) Bg[h] = Bb + ((size_t)(n0+rr+32*h)*Kdim)*2 + gsw;
  const char* Ag[4];                     // per-wave A frag rows (direct)
  for (int i=0;i<4;i++) Ag[i] = Ab + ((size_t)(m0+wm+i*16+l15)*Kdim)*2 + quad*16;

  bf16x8 br[4];
  for (int h=0;h<4;h++) br[h] = *(const bf16x8*)Bg[h];
  for (int h=0;h<4;h++) *(bf16x8*)(BsB + h*4096 + tid*16) = br[h];
  __syncthreads();

  for (int k0=0; k0<Kdim; k0+=64){
    if (k0 < Kdim-64){                   // prefetch next B tile into relay regs
      size_t kb = (size_t)(k0+64)*2;
      for (int h=0;h<4;h++) br[h] = *(const bf16x8*)(Bg[h]+kb);
    }
    size_t ka = (size_t)k0*2;
    for (int c=0;c<2;c++){
      bf16x8 af[4], bfr[4];
      for (int i=0;i<4;i++) af[i] = *(const bf16x8*)(Ag[i] + ka + c*64);
      for (int i=0;i<4;i++){
        int nb2 = wn + i*16 + l15;
        bfr[i] = *(const bf16x8*)(BsB + nb2*128 + (((c*4+quad) ^ (nb2&7))<<4));
      }
      if (sw){
        for (int p=0;p<4;p++) for (int q=0;q<4;q++)
          acc[p][q] = __builtin_amdgcn_mfma_f32_16x16x32_bf16(bfr[p], af[q], acc[p][q], 0,0,0);
      } else {
        for (int p=0;p<4;p++) for (int q=0;q<4;q++)
          acc[p][q] = __builtin_amdgcn_mfma_f32_16x16x32_bf16(af[p], bfr[q], acc[p][q], 0,0,0);
      }
    }
    __syncthreads();                     // all waves done reading Bs (lgkm only)
    if (k0 < Kdim-64){
      for (int h=0;h<4;h++) *(bf16x8*)(BsB + h*4096 + tid*16) = br[h];
      __syncthreads();
    }
  }

  if (sw){
    int c3 = (n0 >= 768);
    u16* dst = c3 ? Kw : Qw;
    float scl = c3 ? 1.0f : 0.180336884f;   // Q: 0.125 * log2(e) folded for exp2 path
    int nb = n0 - c3*768;
    for (int p=0;p<4;p++){
      float4 bv4 = *(const float4*)(bias + n0 + wn + p*16 + quad*4);
      int rem = nb + wn + p*16 + quad*4;
      int hh = rem>>6, d0 = rem&63;
      for (int q=0;q<4;q++){
        int mrow = m0 + wm + q*16 + l15;
        int b = mrow>>10, sl = mrow&1023;
        u16x4 pk;
        pk[0]=f2bf((acc[p][q][0]+bv4.x)*scl); pk[1]=f2bf((acc[p][q][1]+bv4.y)*scl);
        pk[2]=f2bf((acc[p][q][2]+bv4.z)*scl); pk[3]=f2bf((acc[p][q][3]+bv4.w)*scl);
        *(u16x4*)(dst + ((size_t)(b*12+hh)*1024 + sl)*64 + d0) = pk;
      }
    }
  } else {
    for (int q=0;q<4;q++){
      float bv = bias[n0+wn+q*16+l15];
      int rem = (n0-1536) + wn + q*16 + l15;
      int hh = rem>>6, d = rem&63;
      for (int p=0;p<4;p++){
        int mrow = m0 + wm + p*16 + quad*4;
        int b = mrow>>10, sl = mrow&1023;
        u16x4 pk;
        for (int r=0;r<4;r++) pk[r] = f2bf(acc[p][q][r] + bv);
        *(u16x4*)(Vtw + ((size_t)(b*12+hh)*64 + d)*1024 + sl) = pk;
      }
    }
  }
}

// ------ flash attention (round-11 proven: single-buffer VGPR relay, 49.3 us) -------
// grid (96 bh, 8 q-tiles), block 256 = 4 waves; each wave owns 32 queries.
// 32KB LDS (5 blocks/CU). Chunk c+1 prefetched global->VGPR during compute of c;
// after the read barrier the relay is ds_written into the same buffers. Neither
// barrier drains global vmcnt. No-max softmax (scores pre-scaled by 0.125*log2e):
// P = exp2(S); denominators via ones-row MFMA. 96 % 8 == 0 -> K/V reads L2-local.
__global__ void __launch_bounds__(256) attn_k(const u16* __restrict__ Qw,
      const u16* __restrict__ Kw, const u16* __restrict__ Vtw, u16* __restrict__ ctx){
  __shared__ u16 Ks[4096];     // [64 key][64 d]  128B rows, granule ^= key&7
  __shared__ u16 Vts[4096];    // [64 d][64 key]  128B rows, granule ^= d&7
  __shared__ u16 Ps[4][2048];  // per-wave P/O: [32 q][64] 128B rows, granule ^= q&7
  int tid = threadIdx.x, wave = tid>>6, lane = tid&63;
  int l15 = lane&15, quad = lane>>4;
  int bh = blockIdx.x;
  int q0w = blockIdx.y*128 + wave*32;
  const u16* Qb  = Qw + (size_t)bh*65536;
  const char* KbB = (const char*)(Kw + (size_t)bh*65536);
  const char* VbB = (const char*)(Vtw + (size_t)bh*65536);
  char* KsB = (char*)Ks; char* VtsB = (char*)Vts;
  char* PwB = (char*)(&Ps[wave][0]);

  bf16x8 qa[2][2];
  for (int qt=0;qt<2;qt++) for (int c=0;c<2;c++)
    qa[qt][c] = *(const bf16x8*)(Qb + (size_t)(q0w+qt*16+l15)*64 + c*32 + quad*8);

  bf16x8 ones_f;
  for (int t=0;t<8;t++) ones_f[t] = (short)0x3F80;   // bf16 1.0

  f32x4 oacc[4][2] = {};   // [dt][qt]: O^T row d=dt*16+quad*4+r, col q=qt*16+l15
  f32x4 lacc[2] = {};      // denominator (all r equal)

  int rr = tid>>3, gs = tid&7;          // staging: row-in-half / stored granule
  int gsw = (gs ^ (rr&7)) << 4;         // swizzled source granule byte offset
  int ldst = tid*16;
  const char* Kg0 = KbB + (size_t)rr*128      + gsw;   // + c*64*128 per chunk
  const char* Kg1 = KbB + (size_t)(rr+32)*128 + gsw;
  const char* Vg0 = VbB + (size_t)rr*2048      + gsw;  // + c*64*2 per chunk
  const char* Vg1 = VbB + (size_t)(rr+32)*2048 + gsw;

  // stage chunk 0 via relay
  bf16x8 krel0 = *(const bf16x8*)Kg0, krel1 = *(const bf16x8*)Kg1;
  bf16x8 vrel0 = *(const bf16x8*)Vg0, vrel1 = *(const bf16x8*)Vg1;
  *(bf16x8*)(KsB + ldst)  = krel0;  *(bf16x8*)(KsB + 4096 + ldst)  = krel1;
  *(bf16x8*)(VtsB + ldst) = vrel0;  *(bf16x8*)(VtsB + 4096 + ldst) = vrel1;
  __syncthreads();

  for (int c=0; c<16; c++){
    if (c < 15){                          // prefetch chunk c+1 into relay regs
      size_t kk = (size_t)(c+1)*64;
      krel0 = *(const bf16x8*)(Kg0 + kk*128);
      krel1 = *(const bf16x8*)(Kg1 + kk*128);
      vrel0 = *(const bf16x8*)(Vg0 + kk*2);
      vrel1 = *(const bf16x8*)(Vg1 + kk*2);
    }
    // ---- QK: S^T[64k x 32q], K-dim 64 in two 32-chunks ----
    f32x4 st[4][2];
    for (int kt=0;kt<4;kt++){
      int key = kt*16 + l15;
      const char* krow = KsB + key*128;
      bf16x8 ka0 = *(const bf16x8*)(krow + (((quad  ) ^ (key&7))<<4));
      bf16x8 ka1 = *(const bf16x8*)(krow + (((quad+4) ^ (key&7))<<4));
      for (int qt=0;qt<2;qt++){
        f32x4 s = {};
        s = __builtin_amdgcn_mfma_f32_16x16x32_bf16(ka0, qa[qt][0], s, 0,0,0);
        s = __builtin_amdgcn_mfma_f32_16x16x32_bf16(ka1, qa[qt][1], s, 0,0,0);
        st[kt][qt] = s;
      }
    }
    // ---- P = exp2(st), pack to bf16, stage to LDS ----
    for (int qt=0;qt<2;qt++){
      int q = qt*16 + l15;
      for (int kt=0;kt<4;kt++){
        u16x4 pk;
        for (int r=0;r<4;r++) pk[r] = f2bf_fast(exp2f(st[kt][qt][r]));
        int g = kt*2 + (quad>>1);
        *(u16x4*)(PwB + q*128 + ((g ^ (l15&7))<<4) + (quad&1)*8) = pk;
      }
    }
    // ---- PV: O^T += V^T * P^T ; l += ones * P^T ----
    bf16x8 bp[2][2];
    for (int qt=0;qt<2;qt++){
      int q = qt*16 + l15;
      bp[qt][0] = *(const bf16x8*)(PwB + q*128 + (((quad  ) ^ (l15&7))<<4));
      bp[qt][1] = *(const bf16x8*)(PwB + q*128 + (((quad+4) ^ (l15&7))<<4));
      lacc[qt] = __builtin_amdgcn_mfma_f32_16x16x32_bf16(ones_f, bp[qt][0], lacc[qt], 0,0,0);
      lacc[qt] = __builtin_amdgcn_mfma_f32_16x16x32_bf16(ones_f, bp[qt][1], lacc[qt], 0,0,0);
    }
    for (int dt=0;dt<4;dt++){
      int d = dt*16 + l15;
      const char* vrow = VtsB + d*128;
      bf16x8 av0 = *(const bf16x8*)(vrow + (((quad  ) ^ (d&7))<<4));
      bf16x8 av1 = *(const bf16x8*)(vrow + (((quad+4) ^ (d&7))<<4));
      for (int qt=0;qt<2;qt++){
        oacc[dt][qt] = __builtin_amdgcn_mfma_f32_16x16x32_bf16(av0, bp[qt][0], oacc[dt][qt], 0,0,0);
        oacc[dt][qt] = __builtin_amdgcn_mfma_f32_16x16x32_bf16(av1, bp[qt][1], oacc[dt][qt], 0,0,0);
      }
    }
    __syncthreads();                      // all waves done reading Ks/Vts (lgkm only)
    if (c < 15){
      *(bf16x8*)(KsB + ldst)  = krel0;  *(bf16x8*)(KsB + 4096 + ldst)  = krel1;
      *(bf16x8*)(VtsB + ldst) = vrel0;  *(bf16x8*)(VtsB + 4096 + ldst) = vrel1;
      __syncthreads();                    // staging visible (lgkm only)
    }
  }

  // ---- epilogue: normalize, transpose O^T->O via per-wave Ps, coalesced store ----
  float rinv[2] = { 1.0f/lacc[0][0], 1.0f/lacc[1][0] };
  int b = bh/12, hh = bh - b*12;
  for (int qt=0;qt<2;qt++){
    int q = qt*16 + l15;
    for (int dt=0;dt<4;dt++){
      u16x4 pk;
      for (int r=0;r<4;r++) pk[r] = f2bf_fast(oacc[dt][qt][r]*rinv[qt]);
      int g = dt*2 + (quad>>1);
      *(u16x4*)(PwB + q*128 + ((g ^ (l15&7))<<4) + (quad&1)*8) = pk;
    }
  }
  char* ctxB = (char*)ctx;
  for (int ro=0; ro<4; ro++){            // 32 rows x 8 granules = 4 rounds of 64 lanes
    int q = ro*8 + (lane>>3);
    int gg = lane&7;
    bf16x8 v = *(const bf16x8*)(PwB + q*128 + ((gg ^ (q&7))<<4));
    size_t tok = (size_t)b*1024 + blockIdx.y*128 + wave*32 + q;
    *(bf16x8*)(ctxB + (tok*768 + hh*64 + gg*8)*2) = v;
  }
}

// ----- proj GEMM (round-12): A direct-from-global, B LDS + VGPR relay -------------
// tile 128m x 64n, grid 768 = 8 xcd x 8 mg x 12 n. 4 waves: each 64m x 32n.
__global__ void __launch_bounds__(256) proj_gemm(const u16* __restrict__ A,
      const u16* __restrict__ BT, const float* __restrict__ bias,
      float* __restrict__ of){
  __shared__ u16 Bs[4096];   // [64 n][64 k] = 8KB
  const int Kdim = 768;
  int tid = threadIdx.x, lane = tid&63, wave = tid>>6;
  int l15 = lane&15, quad = lane>>4;
  int bid = blockIdx.x;
  int xcd = bid & 7, slot = bid >> 3;
  int mg = slot & 7, nIdx = slot >> 3;
  int m0 = (xcd*8 + mg)*128, n0 = nIdx*64;
  int wm = (wave>>1)*64, wn = (wave&1)*32;
  f32x4 acc[4][2] = {};
  const char* Ab = (const char*)A; const char* Bb = (const char*)BT;
  char* BsB = (char*)Bs;
  int rr = tid>>3, gs = tid&7;
  int gsw = (gs ^ (rr&7)) << 4;
  const char* Bg[2];
  for (int h=0;h<2;h++) Bg[h] = Bb + ((size_t)(n0+rr+32*h)*Kdim)*2 + gsw;
  const char* Ag[4];
  for (int i=0;i<4;i++) Ag[i] = Ab + ((size_t)(m0+wm+i*16+l15)*Kdim)*2 + quad*16;
  bf16x8 br[2];
  for (int h=0;h<2;h++) br[h] = *(const bf16x8*)Bg[h];
  for (int h=0;h<2;h++) *(bf16x8*)(BsB + h*4096 + tid*16) = br[h];
  __syncthreads();

  for (int k0=0; k0<Kdim; k0+=64){
    if (k0 < Kdim-64){
      size_t kb = (size_t)(k0+64)*2;
      for (int h=0;h<2;h++) br[h] = *(const bf16x8*)(Bg[h]+kb);
    }
    size_t ka = (size_t)k0*2;
    for (int c=0;c<2;c++){
      bf16x8 af[4], bfr[2];
      for (int i=0;i<4;i++) af[i] = *(const bf16x8*)(Ag[i] + ka + c*64);
      for (int j=0;j<2;j++){
        int nb2 = wn + j*16 + l15;
        bfr[j] = *(const bf16x8*)(BsB + nb2*128 + (((c*4+quad) ^ (nb2&7))<<4));
      }
      for (int i=0;i<4;i++)
        for (int j=0;j<2;j++)
          acc[i][j] = __builtin_amdgcn_mfma_f32_16x16x32_bf16(af[i], bfr[j], acc[i][j], 0,0,0);
    }
    __syncthreads();
    if (k0 < Kdim-64){
      for (int h=0;h<2;h++) *(bf16x8*)(BsB + h*4096 + tid*16) = br[h];
      __syncthreads();
    }
  }
  float bv[2];
  for (int j=0;j<2;j++) bv[j] = bias[n0+wn+j*16+l15];
  for (int i=0;i<4;i++){
    int mb = m0 + wm + i*16 + quad*4;
    for (int j=0;j<2;j++){
      int ncol = wn + j*16 + l15;
      for (int r=0;r<4;r++)
        of[(size_t)(mb+r)*768 + n0 + ncol] = acc[i][j][r] + bv[j];
    }
  }
}

extern "C" void kernel_launch(void* const* d_in, const int* in_sizes, int n_in,
                              void* d_out, int out_size, void* d_ws, size_t ws_size,
                              hipStream_t stream){
  const float* hidden = (const float*)d_in[0];
  const float* wqkv   = (const float*)d_in[1];
  const float* bqkv   = (const float*)d_in[2];
  const float* wproj  = (const float*)d_in[3];
  const float* bproj  = (const float*)d_in[4];
  float* out = (float*)d_out;
  char* ws = (char*)d_ws;
  u16* Acv    = (u16*)(ws);                                   // [8192][768] bf16
  u16* WqkvT  = (u16*)(ws + 12582912);                        // 2304x768
  u16* WprojT = (u16*)(ws + 12582912 + 3538944);              // 768x768
  char* base2 = ws + 12582912 + 3538944 + 1179648;
  u16* Qw     = (u16*)(base2);                                // [96][1024][64] (pre-scaled)
  u16* Kw     = (u16*)(base2 + 12582912);                     // [96][1024][64]
  u16* Vtw    = (u16*)(base2 + (size_t)2*12582912);           // [96][64][1024]
  u16* ctx    = (u16*)(base2 + (size_t)3*12582912);           // [8192][768] bf16

  prep_k<<<5376, 256, 0, stream>>>(hidden, wqkv, wproj, Acv, WqkvT, WprojT);
  qkv_gemm<<<1152, 256, 0, stream>>>(Acv, WqkvT, bqkv, Qw, Kw, Vtw);
  attn_k<<<dim3(96,8), 256, 0, stream>>>(Qw, Kw, Vtw, ctx);
  proj_gemm<<<768, 256, 0, stream>>>(ctx, WprojT, bproj, out);
}

// Round 13
// 185.371 us; speedup vs baseline: 1.3421x; 1.3421x over previous
//
#include <hip/hip_runtime.h>
#include <stdint.h>

typedef unsigned short u16;
typedef __attribute__((ext_vector_type(8))) short bf16x8;   // 8 bf16 = 4 VGPR (MFMA A/B frag)
typedef __attribute__((ext_vector_type(4))) float f32x4;    // MFMA C/D frag
typedef __attribute__((ext_vector_type(4))) unsigned short u16x4;

#define DEVI static __device__ __forceinline__

DEVI u16 f2bf(float f){ union{float f; unsigned u;} x; x.f=f;
  unsigned r = x.u + 0x7FFFu + ((x.u>>16)&1u); return (u16)(r>>16); }
// round-half-up bf16 (2 VALU ops): max bias 0.5 ulp, fine at this tolerance
DEVI u16 f2bf_fast(float f){ union{float f; unsigned u;} x; x.f=f;
  return (u16)((x.u + 0x8000u)>>16); }

// ---------------- prep: hidden f32->bf16 + both weight transposes, one dispatch ----
__global__ void __launch_bounds__(256) prep_k(const float* __restrict__ hidden,
      const float* __restrict__ wqkv, const float* __restrict__ wproj,
      u16* __restrict__ Acv, u16* __restrict__ WqkvT, u16* __restrict__ WprojT){
  __shared__ u16 t[32][33];
  int bid = blockIdx.x, tid = threadIdx.x;
  if (bid < 3072){                       // cvt hidden: 8 floats/thread
    int i = bid*2048 + tid*8;
    float4 a = *(const float4*)(hidden+i), b = *(const float4*)(hidden+i+4);
    u16x4 lo = { f2bf(a.x), f2bf(a.y), f2bf(a.z), f2bf(a.w) };
    u16x4 hi = { f2bf(b.x), f2bf(b.y), f2bf(b.z), f2bf(b.w) };
    *(u16x4*)(Acv+i) = lo; *(u16x4*)(Acv+i+4) = hi;
    return;
  }
  const float* in; u16* outp; int C, bx, by;
  if (bid < 4800){ int tt = bid-3072; bx = tt%72; by = tt/72; in = wqkv;  outp = WqkvT;  C = 2304; }
  else           { int tt = bid-4800; bx = tt%24; by = tt/24; in = wproj; outp = WprojT; C = 768;  }
  int tx = tid&31, ty = tid>>5;          // 32 x 8
  int c0 = bx*32, r0 = by*32;
  for (int i=0;i<4;i++)
    t[ty+i*8][tx] = f2bf(in[(size_t)(r0+ty+i*8)*C + c0+tx]);
  __syncthreads();
  for (int i=0;i<4;i++) outp[(size_t)(c0+ty+i*8)*768 + r0+tx] = t[tx][ty+i*8];
}

// ------- merged QKV GEMM (round-11 proven, 49.4 us): A+B VGPR-relay + LDS ----------
// Tile k+1 is loaded global->VGPR (plain b128 loads, no waitcnt in barrier path)
// while tile k computes from LDS; after the read-barrier the relay regs are
// ds_written. Barriers wait only on LDS ops -> no vmcnt(0) global drain.
// XCD-aware decode (xcd=bid&7 owns 8 m-tiles x all n): A panel L2-resident.
//  n0 < 1536 (Q/K): SWAPPED MFMA operands (reg r along n=d) -> u16x4 into [bh][s][d]
//  n0 >= 1536 (V): normal order (reg r along m=s) -> u16x4 into Vt[bh][d][s]
__global__ void __launch_bounds__(256) qkv_gemm(const u16* __restrict__ A,
      const u16* __restrict__ BT, const float* __restrict__ bias,
      u16* __restrict__ Qw, u16* __restrict__ Kw, u16* __restrict__ Vtw){
  __shared__ u16 As[8192];   // [128 m][64 k] 128B rows, granule g holds global g^(row&7)
  __shared__ u16 Bs[8192];
  const int Kdim = 768;
  int tid = threadIdx.x, lane = tid&63, wave = tid>>6;
  int l15 = lane&15, quad = lane>>4;
  int bid = blockIdx.x;                  // 1152 = 8 xcd x 8 mg x 18 n
  int xcd = bid & 7, slot = bid >> 3;
  int mg = slot & 7, nIdx = slot >> 3;
  int m0 = (xcd*8 + mg)*128, n0 = nIdx*128;
  int wm = (wave>>1)*64, wn = (wave&1)*64;
  bool sw = (n0 < 1536);
  f32x4 acc[4][4] = {};
  const char* Ab = (const char*)A; const char* Bb = (const char*)BT;
  char* AsB = (char*)As; char* BsB = (char*)Bs;
  int rr = tid>>3, gs = tid&7;
  int gsw = (gs ^ (rr&7)) << 4;
  const char* Ag[4]; const char* Bg[4];
  for (int h=0;h<4;h++){
    Ag[h] = Ab + ((size_t)(m0+rr+32*h)*Kdim)*2 + gsw;
    Bg[h] = Bb + ((size_t)(n0+rr+32*h)*Kdim)*2 + gsw;
  }
  bf16x8 ar[4], br[4];
  for (int h=0;h<4;h++){ ar[h] = *(const bf16x8*)Ag[h]; br[h] = *(const bf16x8*)Bg[h]; }
  for (int h=0;h<4;h++){
    *(bf16x8*)(AsB + h*4096 + tid*16) = ar[h];
    *(bf16x8*)(BsB + h*4096 + tid*16) = br[h];
  }
  __syncthreads();

  for (int k0=0; k0<Kdim; k0+=64){
    if (k0 < Kdim-64){                   // prefetch next tile into relay regs
      size_t kb = (size_t)(k0+64)*2;
      for (int h=0;h<4;h++){ ar[h] = *(const bf16x8*)(Ag[h]+kb); br[h] = *(const bf16x8*)(Bg[h]+kb); }
    }
    for (int c=0;c<2;c++){               // compute tile k from LDS
      bf16x8 af[4], bfr[4];
      for (int i=0;i<4;i++){
        int ma = wm + i*16 + l15, nb2 = wn + i*16 + l15;
        af[i]  = *(const bf16x8*)(AsB + ma*128  + (((c*4+quad) ^ (ma&7))<<4));
        bfr[i] = *(const bf16x8*)(BsB + nb2*128 + (((c*4+quad) ^ (nb2&7))<<4));
      }
      if (sw){
        for (int p=0;p<4;p++) for (int q=0;q<4;q++)
          acc[p][q] = __builtin_amdgcn_mfma_f32_16x16x32_bf16(bfr[p], af[q], acc[p][q], 0,0,0);
      } else {
        for (int p=0;p<4;p++) for (int q=0;q<4;q++)
          acc[p][q] = __builtin_amdgcn_mfma_f32_16x16x32_bf16(af[p], bfr[q], acc[p][q], 0,0,0);
      }
    }
    __syncthreads();                     // all waves done reading LDS (lgkm only)
    if (k0 < Kdim-64){
      for (int h=0;h<4;h++){             // relay -> LDS (waits vmcnt of prefetch,
        *(bf16x8*)(AsB + h*4096 + tid*16) = ar[h];   // loads had whole MFMA phase)
        *(bf16x8*)(BsB + h*4096 + tid*16) = br[h];
      }
      __syncthreads();
    }
  }

  if (sw){
    int c3 = (n0 >= 768);
    u16* dst = c3 ? Kw : Qw;
    float scl = c3 ? 1.0f : 0.180336884f;   // Q: 0.125 * log2(e) folded for exp2 path
    int nb = n0 - c3*768;
    for (int p=0;p<4;p++){
      float4 bv4 = *(const float4*)(bias + n0 + wn + p*16 + quad*4);
      int rem = nb + wn + p*16 + quad*4;
      int hh = rem>>6, d0 = rem&63;
      for (int q=0;q<4;q++){
        int mrow = m0 + wm + q*16 + l15;
        int b = mrow>>10, sl = mrow&1023;
        u16x4 pk;
        pk[0]=f2bf((acc[p][q][0]+bv4.x)*scl); pk[1]=f2bf((acc[p][q][1]+bv4.y)*scl);
        pk[2]=f2bf((acc[p][q][2]+bv4.z)*scl); pk[3]=f2bf((acc[p][q][3]+bv4.w)*scl);
        *(u16x4*)(dst + ((size_t)(b*12+hh)*1024 + sl)*64 + d0) = pk;
      }
    }
  } else {
    for (int q=0;q<4;q++){
      float bv = bias[n0+wn+q*16+l15];
      int rem = (n0-1536) + wn + q*16 + l15;
      int hh = rem>>6, d = rem&63;
      for (int p=0;p<4;p++){
        int mrow = m0 + wm + p*16 + quad*4;
        int b = mrow>>10, sl = mrow&1023;
        u16x4 pk;
        for (int r=0;r<4;r++) pk[r] = f2bf(acc[p][q][r] + bv);
        *(u16x4*)(Vtw + ((size_t)(b*12+hh)*64 + d)*1024 + sl) = pk;
      }
    }
  }
}

// ------ flash attention (round-11 proven + raw v_exp_f32) --------------------------
// grid (96 bh, 8 q-tiles), block 256 = 4 waves; each wave owns 32 queries.
// 32KB LDS (grid gives 3 blocks/CU). Chunk c+1 prefetched global->VGPR during
// compute of c; after the read barrier the relay is ds_written into the same
// buffers. Neither barrier drains global vmcnt. No-max softmax (scores pre-scaled
// by 0.125*log2e): P = exp2(S) via __builtin_amdgcn_exp2f (bare v_exp_f32, no libm
// range fixup -- inputs bounded). Denominators via ones-row MFMA. 96 % 8 == 0 ->
// all q-blocks of a bh share an XCD, K/V reads L2-local.
__global__ void __launch_bounds__(256) attn_k(const u16* __restrict__ Qw,
      const u16* __restrict__ Kw, const u16* __restrict__ Vtw, u16* __restrict__ ctx){
  __shared__ u16 Ks[4096];     // [64 key][64 d]  128B rows, granule ^= key&7
  __shared__ u16 Vts[4096];    // [64 d][64 key]  128B rows, granule ^= d&7
  __shared__ u16 Ps[4][2048];  // per-wave P/O: [32 q][64] 128B rows, granule ^= q&7
  int tid = threadIdx.x, wave = tid>>6, lane = tid&63;
  int l15 = lane&15, quad = lane>>4;
  int bh = blockIdx.x;
  int q0w = blockIdx.y*128 + wave*32;
  const u16* Qb  = Qw + (size_t)bh*65536;
  const char* KbB = (const char*)(Kw + (size_t)bh*65536);
  const char* VbB = (const char*)(Vtw + (size_t)bh*65536);
  char* KsB = (char*)Ks; char* VtsB = (char*)Vts;
  char* PwB = (char*)(&Ps[wave][0]);

  bf16x8 qa[2][2];
  for (int qt=0;qt<2;qt++) for (int c=0;c<2;c++)
    qa[qt][c] = *(const bf16x8*)(Qb + (size_t)(q0w+qt*16+l15)*64 + c*32 + quad*8);

  bf16x8 ones_f;
  for (int t=0;t<8;t++) ones_f[t] = (short)0x3F80;   // bf16 1.0

  f32x4 oacc[4][2] = {};   // [dt][qt]: O^T row d=dt*16+quad*4+r, col q=qt*16+l15
  f32x4 lacc[2] = {};      // denominator (all r equal)

  int rr = tid>>3, gs = tid&7;          // staging: row-in-half / stored granule
  int gsw = (gs ^ (rr&7)) << 4;         // swizzled source granule byte offset
  int ldst = tid*16;
  const char* Kg0 = KbB + (size_t)rr*128      + gsw;   // + c*64*128 per chunk
  const char* Kg1 = KbB + (size_t)(rr+32)*128 + gsw;
  const char* Vg0 = VbB + (size_t)rr*2048      + gsw;  // + c*64*2 per chunk
  const char* Vg1 = VbB + (size_t)(rr+32)*2048 + gsw;

  // stage chunk 0 via relay
  bf16x8 krel0 = *(const bf16x8*)Kg0, krel1 = *(const bf16x8*)Kg1;
  bf16x8 vrel0 = *(const bf16x8*)Vg0, vrel1 = *(const bf16x8*)Vg1;
  *(bf16x8*)(KsB + ldst)  = krel0;  *(bf16x8*)(KsB + 4096 + ldst)  = krel1;
  *(bf16x8*)(VtsB + ldst) = vrel0;  *(bf16x8*)(VtsB + 4096 + ldst) = vrel1;
  __syncthreads();

  for (int c=0; c<16; c++){
    if (c < 15){                          // prefetch chunk c+1 into relay regs
      size_t kk = (size_t)(c+1)*64;
      krel0 = *(const bf16x8*)(Kg0 + kk*128);
      krel1 = *(const bf16x8*)(Kg1 + kk*128);
      vrel0 = *(const bf16x8*)(Vg0 + kk*2);
      vrel1 = *(const bf16x8*)(Vg1 + kk*2);
    }
    // ---- QK: S^T[64k x 32q], K-dim 64 in two 32-chunks ----
    f32x4 st[4][2];
    for (int kt=0;kt<4;kt++){
      int key = kt*16 + l15;
      const char* krow = KsB + key*128;
      bf16x8 ka0 = *(const bf16x8*)(krow + (((quad  ) ^ (key&7))<<4));
      bf16x8 ka1 = *(const bf16x8*)(krow + (((quad+4) ^ (key&7))<<4));
      for (int qt=0;qt<2;qt++){
        f32x4 s = {};
        s = __builtin_amdgcn_mfma_f32_16x16x32_bf16(ka0, qa[qt][0], s, 0,0,0);
        s = __builtin_amdgcn_mfma_f32_16x16x32_bf16(ka1, qa[qt][1], s, 0,0,0);
        st[kt][qt] = s;
      }
    }
    // ---- P = exp2(st) (raw v_exp_f32), pack to bf16, stage to LDS ----
    for (int qt=0;qt<2;qt++){
      int q = qt*16 + l15;
      for (int kt=0;kt<4;kt++){
        u16x4 pk;
        for (int r=0;r<4;r++) pk[r] = f2bf_fast(__builtin_amdgcn_exp2f(st[kt][qt][r]));
        int g = kt*2 + (quad>>1);
        *(u16x4*)(PwB + q*128 + ((g ^ (l15&7))<<4) + (quad&1)*8) = pk;
      }
    }
    // ---- PV: O^T += V^T * P^T ; l += ones * P^T ----
    bf16x8 bp[2][2];
    for (int qt=0;qt<2;qt++){
      int q = qt*16 + l15;
      bp[qt][0] = *(const bf16x8*)(PwB + q*128 + (((quad  ) ^ (l15&7))<<4));
      bp[qt][1] = *(const bf16x8*)(PwB + q*128 + (((quad+4) ^ (l15&7))<<4));
      lacc[qt] = __builtin_amdgcn_mfma_f32_16x16x32_bf16(ones_f, bp[qt][0], lacc[qt], 0,0,0);
      lacc[qt] = __builtin_amdgcn_mfma_f32_16x16x32_bf16(ones_f, bp[qt][1], lacc[qt], 0,0,0);
    }
    for (int dt=0;dt<4;dt++){
      int d = dt*16 + l15;
      const char* vrow = VtsB + d*128;
      bf16x8 av0 = *(const bf16x8*)(vrow + (((quad  ) ^ (d&7))<<4));
      bf16x8 av1 = *(const bf16x8*)(vrow + (((quad+4) ^ (d&7))<<4));
      for (int qt=0;qt<2;qt++){
        oacc[dt][qt] = __builtin_amdgcn_mfma_f32_16x16x32_bf16(av0, bp[qt][0], oacc[dt][qt], 0,0,0);
        oacc[dt][qt] = __builtin_amdgcn_mfma_f32_16x16x32_bf16(av1, bp[qt][1], oacc[dt][qt], 0,0,0);
      }
    }
    __syncthreads();                      // all waves done reading Ks/Vts (lgkm only)
    if (c < 15){
      *(bf16x8*)(KsB + ldst)  = krel0;  *(bf16x8*)(KsB + 4096 + ldst)  = krel1;
      *(bf16x8*)(VtsB + ldst) = vrel0;  *(bf16x8*)(VtsB + 4096 + ldst) = vrel1;
      __syncthreads();                    // staging visible (lgkm only)
    }
  }

  // ---- epilogue: normalize, transpose O^T->O via per-wave Ps, coalesced store ----
  float rinv[2] = { 1.0f/lacc[0][0], 1.0f/lacc[1][0] };
  int b = bh/12, hh = bh - b*12;
  for (int qt=0;qt<2;qt++){
    int q = qt*16 + l15;
    for (int dt=0;dt<4;dt++){
      u16x4 pk;
      for (int r=0;r<4;r++) pk[r] = f2bf_fast(oacc[dt][qt][r]*rinv[qt]);
      int g = dt*2 + (quad>>1);
      *(u16x4*)(PwB + q*128 + ((g ^ (l15&7))<<4) + (quad&1)*8) = pk;
    }
  }
  char* ctxB = (char*)ctx;
  for (int ro=0; ro<4; ro++){            // 32 rows x 8 granules = 4 rounds of 64 lanes
    int q = ro*8 + (lane>>3);
    int gg = lane&7;
    bf16x8 v = *(const bf16x8*)(PwB + q*128 + ((gg ^ (q&7))<<4));
    size_t tok = (size_t)b*1024 + blockIdx.y*128 + wave*32 + q;
    *(bf16x8*)(ctxB + (tok*768 + hh*64 + gg*8)*2) = v;
  }
}

// -------- proj GEMM (round-11 proven): A+B VGPR-relay + LDS, out f32 --------------
// tile 128m x 64n, grid 768 = 8 xcd x 8 mg x 12 n. 4 waves: each 64m x 32n.
__global__ void __launch_bounds__(256) proj_gemm(const u16* __restrict__ A,
      const u16* __restrict__ BT, const float* __restrict__ bias,
      float* __restrict__ of){
  __shared__ u16 As[8192];   // [128 m][64 k]
  __shared__ u16 Bs[4096];   // [64 n][64 k]
  const int Kdim = 768;
  int tid = threadIdx.x, lane = tid&63, wave = tid>>6;
  int l15 = lane&15, quad = lane>>4;
  int bid = blockIdx.x;
  int xcd = bid & 7, slot = bid >> 3;
  int mg = slot & 7, nIdx = slot >> 3;
  int m0 = (xcd*8 + mg)*128, n0 = nIdx*64;
  int wm = (wave>>1)*64, wn = (wave&1)*32;
  f32x4 acc[4][2] = {};
  const char* Ab = (const char*)A; const char* Bb = (const char*)BT;
  char* AsB = (char*)As; char* BsB = (char*)Bs;
  int rr = tid>>3, gs = tid&7;
  int gsw = (gs ^ (rr&7)) << 4;
  const char* Ag[4]; const char* Bg[2];
  for (int h=0;h<4;h++) Ag[h] = Ab + ((size_t)(m0+rr+32*h)*Kdim)*2 + gsw;
  for (int h=0;h<2;h++) Bg[h] = Bb + ((size_t)(n0+rr+32*h)*Kdim)*2 + gsw;
  bf16x8 ar[4], br[2];
  for (int h=0;h<4;h++) ar[h] = *(const bf16x8*)Ag[h];
  for (int h=0;h<2;h++) br[h] = *(const bf16x8*)Bg[h];
  for (int h=0;h<4;h++) *(bf16x8*)(AsB + h*4096 + tid*16) = ar[h];
  for (int h=0;h<2;h++) *(bf16x8*)(BsB + h*4096 + tid*16) = br[h];
  __syncthreads();

  for (int k0=0; k0<Kdim; k0+=64){
    if (k0 < Kdim-64){
      size_t kb = (size_t)(k0+64)*2;
      for (int h=0;h<4;h++) ar[h] = *(const bf16x8*)(Ag[h]+kb);
      for (int h=0;h<2;h++) br[h] = *(const bf16x8*)(Bg[h]+kb);
    }
    for (int c=0;c<2;c++){
      bf16x8 af[4], bfr[2];
      for (int i=0;i<4;i++){
        int ma = wm + i*16 + l15;
        af[i] = *(const bf16x8*)(AsB + ma*128 + (((c*4+quad) ^ (ma&7))<<4));
      }
      for (int j=0;j<2;j++){
        int nb2 = wn + j*16 + l15;
        bfr[j] = *(const bf16x8*)(BsB + nb2*128 + (((c*4+quad) ^ (nb2&7))<<4));
      }
      for (int i=0;i<4;i++)
        for (int j=0;j<2;j++)
          acc[i][j] = __builtin_amdgcn_mfma_f32_16x16x32_bf16(af[i], bfr[j], acc[i][j], 0,0,0);
    }
    __syncthreads();
    if (k0 < Kdim-64){
      for (int h=0;h<4;h++) *(bf16x8*)(AsB + h*4096 + tid*16) = ar[h];
      for (int h=0;h<2;h++) *(bf16x8*)(BsB + h*4096 + tid*16) = br[h];
      __syncthreads();
    }
  }
  float bv[2];
  for (int j=0;j<2;j++) bv[j] = bias[n0+wn+j*16+l15];
  for (int i=0;i<4;i++){
    int mb = m0 + wm + i*16 + quad*4;
    for (int j=0;j<2;j++){
      int ncol = wn + j*16 + l15;
      for (int r=0;r<4;r++)
        of[(size_t)(mb+r)*768 + n0 + ncol] = acc[i][j][r] + bv[j];
    }
  }
}

extern "C" void kernel_launch(void* const* d_in, const int* in_sizes, int n_in,
                              void* d_out, int out_size, void* d_ws, size_t ws_size,
                              hipStream_t stream){
  const float* hidden = (const float*)d_in[0];
  const float* wqkv   = (const float*)d_in[1];
  const float* bqkv   = (const float*)d_in[2];
  const float* wproj  = (const float*)d_in[3];
  const float* bproj  = (const float*)d_in[4];
  float* out = (float*)d_out;
  char* ws = (char*)d_ws;
  u16* Acv    = (u16*)(ws);                                   // [8192][768] bf16
  u16* WqkvT  = (u16*)(ws + 12582912);                        // 2304x768
  u16* WprojT = (u16*)(ws + 12582912 + 3538944);              // 768x768
  char* base2 = ws + 12582912 + 3538944 + 1179648;
  u16* Qw     = (u16*)(base2);                                // [96][1024][64] (pre-scaled)
  u16* Kw     = (u16*)(base2 + 12582912);                     // [96][1024][64]
  u16* Vtw    = (u16*)(base2 + (size_t)2*12582912);           // [96][64][1024]
  u16* ctx    = (u16*)(base2 + (size_t)3*12582912);           // [8192][768] bf16

  prep_k<<<5376, 256, 0, stream>>>(hidden, wqkv, wproj, Acv, WqkvT, WprojT);
  qkv_gemm<<<1152, 256, 0, stream>>>(Acv, WqkvT, bqkv, Qw, Kw, Vtw);
  attn_k<<<dim3(96,8), 256, 0, stream>>>(Qw, Kw, Vtw, ctx);
  proj_gemm<<<768, 256, 0, stream>>>(ctx, WprojT, bproj, out);
}